// Round 2
// baseline (321.641 us; speedup 1.0000x reference)
//
#include <hip/hip_runtime.h>

// AttentionalPoolingMechanism: fused single-pass attention pooling.
// A[64,512] f32, B[64,8192,256] f32, W[256,512] f32, b[256] f32 -> out[64,1,256] f32.
//
// AP = tanh(A@W^T + b); s_t = <AP_b, B[b,t,:]>; w_t = exp(-s_t)/sum; out = sum_t w_t B[b,t,:]
// No max-subtraction needed (reference does bare exp(-R); |s| <~ 40 fits f32).
//
// Pool pass: 16 lanes per row x 4 rows per wave-iteration -> only 4 shfl steps
// finish 4 row-dots at once (vs 6 shfl per row for a full-wave reduce), and 4
// rows of loads are in flight per dependency chain. Fully unrolled with 1-deep
// prefetch so the compiler hoists loads (latency hiding).

#define BATCH 64
#define T_LEN 8192
#define FEAT 512
#define HID 256
#define SPLIT 32                       // blocks per batch in pool pass
#define ROWS_PER_BLOCK (T_LEN / SPLIT) // 256
#define ROWS_PER_WAVE 64
#define ITERS (ROWS_PER_WAVE / 4)      // 16

// ---------------- Kernel 1: AP = tanh(A @ W^T + bias) ----------------
__global__ __launch_bounds__(256) void ap_kernel(const float* __restrict__ A,
                                                 const float* __restrict__ W,
                                                 const float* __restrict__ bias,
                                                 float* __restrict__ AP) {
    const int b = blockIdx.x;
    const int tid = threadIdx.x;

    __shared__ float sA[FEAT];
    __shared__ float sW[HID * 33]; // 256 rows x 32 k, padded stride 33 -> 2-way max (free)

    sA[tid] = A[b * FEAT + tid];
    sA[tid + 256] = A[b * FEAT + tid + 256];

    float acc = 0.0f;
    for (int k0 = 0; k0 < FEAT; k0 += 32) {
        __syncthreads();
        #pragma unroll
        for (int t = 0; t < 8; ++t) {
            int f = t * 256 + tid;
            int h = f >> 3;
            int kq = f & 7;
            float4 v = *(const float4*)(W + (size_t)h * FEAT + k0 + kq * 4);
            float* dst = &sW[h * 33 + kq * 4];
            dst[0] = v.x; dst[1] = v.y; dst[2] = v.z; dst[3] = v.w;
        }
        __syncthreads();
        #pragma unroll
        for (int k = 0; k < 32; ++k)
            acc += sA[k0 + k] * sW[tid * 33 + k];
    }
    acc += bias[tid];
    AP[b * HID + tid] = tanhf(acc);
}

// ---------------- Kernel 2: fused score+exp+weighted-accumulate ----------------
// grid = (SPLIT, BATCH), 256 threads = 4 waves; wave owns 64 consecutive rows.
// sub = lane>>4 picks one of 4 rows per iteration; pos = lane&15 picks the
// float4 column slice (pos + 16j, j=0..3) -> per-instruction 16 contiguous
// lanes read contiguous 256B segments (fully coalesced).
__global__ __launch_bounds__(256, 4) void pool_kernel(const float* __restrict__ B,
                                                      const float* __restrict__ AP,
                                                      float* __restrict__ numP,
                                                      float* __restrict__ denP) {
    const int split = blockIdx.x;
    const int b = blockIdx.y;
    const int tid = threadIdx.x;
    const int wv = tid >> 6;
    const int lane = tid & 63;
    const int sub = lane >> 4;
    const int pos = lane & 15;

    const float4* __restrict__ AP4 = (const float4*)(AP + b * HID);
    const float4 ap0 = AP4[pos];
    const float4 ap1 = AP4[pos + 16];
    const float4 ap2 = AP4[pos + 32];
    const float4 ap3 = AP4[pos + 48];

    const float4* __restrict__ B4 = (const float4*)(B) + (size_t)b * T_LEN * (HID / 4);
    const int row0 = split * ROWS_PER_BLOCK + wv * ROWS_PER_WAVE;

    float4 acc0 = {0.f,0.f,0.f,0.f}, acc1 = {0.f,0.f,0.f,0.f};
    float4 acc2 = {0.f,0.f,0.f,0.f}, acc3 = {0.f,0.f,0.f,0.f};
    float den = 0.0f;

    // prologue: load iteration 0
    const float4* rp = B4 + (size_t)(row0 + sub) * (HID / 4);
    float4 v0 = rp[pos], v1 = rp[pos + 16], v2 = rp[pos + 32], v3 = rp[pos + 48];

    #pragma unroll
    for (int it = 0; it < ITERS; ++it) {
        // 1-deep prefetch (clamped on last iter; redundant load is cache-hot)
        const int nit = (it + 1 < ITERS) ? it + 1 : ITERS - 1;
        const float4* np = B4 + (size_t)(row0 + nit * 4 + sub) * (HID / 4);
        float4 n0 = np[pos], n1 = np[pos + 16], n2 = np[pos + 32], n3 = np[pos + 48];

        float d0 = v0.x*ap0.x + v0.y*ap0.y + v0.z*ap0.z + v0.w*ap0.w;
        float d1 = v1.x*ap1.x + v1.y*ap1.y + v1.z*ap1.z + v1.w*ap1.w;
        float d2 = v2.x*ap2.x + v2.y*ap2.y + v2.z*ap2.z + v2.w*ap2.w;
        float d3 = v3.x*ap3.x + v3.y*ap3.y + v3.z*ap3.z + v3.w*ap3.w;
        float p = (d0 + d1) + (d2 + d3);

        // finish 4 independent row-dots with one 4-step butterfly (16-lane groups)
        p += __shfl_xor(p, 8, 64);
        p += __shfl_xor(p, 4, 64);
        p += __shfl_xor(p, 2, 64);
        p += __shfl_xor(p, 1, 64);

        const float w = __expf(-p);
        acc0.x += w*v0.x; acc0.y += w*v0.y; acc0.z += w*v0.z; acc0.w += w*v0.w;
        acc1.x += w*v1.x; acc1.y += w*v1.y; acc1.z += w*v1.z; acc1.w += w*v1.w;
        acc2.x += w*v2.x; acc2.y += w*v2.y; acc2.z += w*v2.z; acc2.w += w*v2.w;
        acc3.x += w*v3.x; acc3.y += w*v3.y; acc3.z += w*v3.z; acc3.w += w*v3.w;
        den += w;

        v0 = n0; v1 = n1; v2 = n2; v3 = n3;
    }

    // reduce accumulators across the 4 sub-groups (lane bits 4,5)
    #define XRED(x) x += __shfl_xor(x, 16, 64); x += __shfl_xor(x, 32, 64)
    XRED(acc0.x); XRED(acc0.y); XRED(acc0.z); XRED(acc0.w);
    XRED(acc1.x); XRED(acc1.y); XRED(acc1.z); XRED(acc1.w);
    XRED(acc2.x); XRED(acc2.y); XRED(acc2.z); XRED(acc2.w);
    XRED(acc3.x); XRED(acc3.y); XRED(acc3.z); XRED(acc3.w);
    XRED(den);
    #undef XRED

    // combine 4 waves via LDS, write per-block partials
    __shared__ float s_num[4][HID];
    __shared__ float s_den[4];
    if (sub == 0) {
        float4* dst = (float4*)s_num[wv];
        dst[pos]      = acc0;
        dst[pos + 16] = acc1;
        dst[pos + 32] = acc2;
        dst[pos + 48] = acc3;
    }
    if (lane == 0) s_den[wv] = den;
    __syncthreads();

    const int blk = b * SPLIT + split;
    float n = s_num[0][tid] + s_num[1][tid] + s_num[2][tid] + s_num[3][tid];
    numP[(size_t)blk * HID + tid] = n;
    if (tid == 0) denP[blk] = s_den[0] + s_den[1] + s_den[2] + s_den[3];
}

// ---------------- Kernel 3: reduce partials, normalize ----------------
__global__ __launch_bounds__(256) void reduce_kernel(const float* __restrict__ numP,
                                                     const float* __restrict__ denP,
                                                     float* __restrict__ out) {
    const int b = blockIdx.x;
    const int h = threadIdx.x;
    float num = 0.0f, den = 0.0f;
    #pragma unroll
    for (int s = 0; s < SPLIT; ++s) {
        num += numP[(size_t)(b * SPLIT + s) * HID + h];
        den += denP[b * SPLIT + s];
    }
    out[b * HID + h] = num / den;
}

extern "C" void kernel_launch(void* const* d_in, const int* in_sizes, int n_in,
                              void* d_out, int out_size, void* d_ws, size_t ws_size,
                              hipStream_t stream) {
    const float* A = (const float*)d_in[0];    // [64,512]
    const float* B = (const float*)d_in[1];    // [64,8192,256]
    const float* W = (const float*)d_in[2];    // [256,512]
    const float* bias = (const float*)d_in[3]; // [256]
    float* out = (float*)d_out;                // [64,1,256]

    float* AP = (float*)d_ws;
    float* numP = AP + BATCH * HID;
    float* denP = numP + BATCH * SPLIT * HID;

    ap_kernel<<<BATCH, 256, 0, stream>>>(A, W, bias, AP);
    pool_kernel<<<dim3(SPLIT, BATCH), 256, 0, stream>>>(B, AP, numP, denP);
    reduce_kernel<<<BATCH, 256, 0, stream>>>(numP, denP, out);
}

// Round 3
// 123.971 us; speedup vs baseline: 2.5945x; 2.5945x over previous
//
#include <hip/hip_runtime.h>

// AttentionalPoolingMechanism: fused single-pass attention pooling.
// A[64,512] f32, B[64,8192,256] f32, W[256,512] f32, b[256] f32 -> out[64,1,256] f32.
//
// AP = tanh(A@W^T + b); s_t = <AP_b, B[b,t,:]>; w_t = exp(-s_t)/sum; out = sum_t w_t B[b,t,:]
// No max-subtraction needed (reference does bare exp(-R); |s| <~ 40 fits f32).
//
// Pool pass: 16 lanes per row x 4 rows per wave-iteration -> only 4 shfl steps
// finish 4 row-dots at once, and 4 rows of loads are in flight per chain.
// NOTE: no min-waves clamp on launch_bounds — (256,4) capped VGPR at 64 and
// spilled ~484 MB of scratch traffic per dispatch (round-2 post-mortem).

#define BATCH 64
#define T_LEN 8192
#define FEAT 512
#define HID 256
#define SPLIT 32                       // blocks per batch in pool pass
#define ROWS_PER_BLOCK (T_LEN / SPLIT) // 256
#define ROWS_PER_WAVE 64
#define ITERS (ROWS_PER_WAVE / 4)      // 16

// ---------------- Kernel 1: AP = tanh(A @ W^T + bias) ----------------
__global__ __launch_bounds__(256) void ap_kernel(const float* __restrict__ A,
                                                 const float* __restrict__ W,
                                                 const float* __restrict__ bias,
                                                 float* __restrict__ AP) {
    const int b = blockIdx.x;
    const int tid = threadIdx.x;

    __shared__ float sA[FEAT];
    __shared__ float sW[HID * 33]; // 256 rows x 32 k, padded stride 33 -> 2-way max (free)

    sA[tid] = A[b * FEAT + tid];
    sA[tid + 256] = A[b * FEAT + tid + 256];

    float acc = 0.0f;
    for (int k0 = 0; k0 < FEAT; k0 += 32) {
        __syncthreads();
        #pragma unroll
        for (int t = 0; t < 8; ++t) {
            int f = t * 256 + tid;
            int h = f >> 3;
            int kq = f & 7;
            float4 v = *(const float4*)(W + (size_t)h * FEAT + k0 + kq * 4);
            float* dst = &sW[h * 33 + kq * 4];
            dst[0] = v.x; dst[1] = v.y; dst[2] = v.z; dst[3] = v.w;
        }
        __syncthreads();
        #pragma unroll
        for (int k = 0; k < 32; ++k)
            acc += sA[k0 + k] * sW[tid * 33 + k];
    }
    acc += bias[tid];
    AP[b * HID + tid] = tanhf(acc);
}

// ---------------- Kernel 2: fused score+exp+weighted-accumulate ----------------
// grid = (SPLIT, BATCH), 256 threads = 4 waves; wave owns 64 consecutive rows.
// sub = lane>>4 picks one of 4 rows per iteration; pos = lane&15 picks the
// float4 column slice (pos + 16j, j=0..3) -> per-instruction 16 contiguous
// lanes read contiguous 256B segments across 4 consecutive rows (coalesced).
__global__ __launch_bounds__(256) void pool_kernel(const float* __restrict__ B,
                                                   const float* __restrict__ AP,
                                                   float* __restrict__ numP,
                                                   float* __restrict__ denP) {
    const int split = blockIdx.x;
    const int b = blockIdx.y;
    const int tid = threadIdx.x;
    const int wv = tid >> 6;
    const int lane = tid & 63;
    const int sub = lane >> 4;
    const int pos = lane & 15;

    const float4* __restrict__ AP4 = (const float4*)(AP + b * HID);
    const float4 ap0 = AP4[pos];
    const float4 ap1 = AP4[pos + 16];
    const float4 ap2 = AP4[pos + 32];
    const float4 ap3 = AP4[pos + 48];

    const float4* __restrict__ B4 = (const float4*)(B) + (size_t)b * T_LEN * (HID / 4);
    const int row0 = split * ROWS_PER_BLOCK + wv * ROWS_PER_WAVE;

    float4 acc0 = {0.f,0.f,0.f,0.f}, acc1 = {0.f,0.f,0.f,0.f};
    float4 acc2 = {0.f,0.f,0.f,0.f}, acc3 = {0.f,0.f,0.f,0.f};
    float den = 0.0f;

    // prologue: load iteration 0
    const float4* rp = B4 + (size_t)(row0 + sub) * (HID / 4);
    float4 v0 = rp[pos], v1 = rp[pos + 16], v2 = rp[pos + 32], v3 = rp[pos + 48];

    #pragma unroll
    for (int it = 0; it < ITERS; ++it) {
        // 1-deep prefetch (clamped on last iter; redundant load is cache-hot)
        const int nit = (it + 1 < ITERS) ? it + 1 : ITERS - 1;
        const float4* np = B4 + (size_t)(row0 + nit * 4 + sub) * (HID / 4);
        float4 n0 = np[pos], n1 = np[pos + 16], n2 = np[pos + 32], n3 = np[pos + 48];

        float d0 = v0.x*ap0.x + v0.y*ap0.y + v0.z*ap0.z + v0.w*ap0.w;
        float d1 = v1.x*ap1.x + v1.y*ap1.y + v1.z*ap1.z + v1.w*ap1.w;
        float d2 = v2.x*ap2.x + v2.y*ap2.y + v2.z*ap2.z + v2.w*ap2.w;
        float d3 = v3.x*ap3.x + v3.y*ap3.y + v3.z*ap3.z + v3.w*ap3.w;
        float p = (d0 + d1) + (d2 + d3);

        // finish 4 independent row-dots with one 4-step butterfly (16-lane groups)
        p += __shfl_xor(p, 8, 64);
        p += __shfl_xor(p, 4, 64);
        p += __shfl_xor(p, 2, 64);
        p += __shfl_xor(p, 1, 64);

        const float w = __expf(-p);
        acc0.x += w*v0.x; acc0.y += w*v0.y; acc0.z += w*v0.z; acc0.w += w*v0.w;
        acc1.x += w*v1.x; acc1.y += w*v1.y; acc1.z += w*v1.z; acc1.w += w*v1.w;
        acc2.x += w*v2.x; acc2.y += w*v2.y; acc2.z += w*v2.z; acc2.w += w*v2.w;
        acc3.x += w*v3.x; acc3.y += w*v3.y; acc3.z += w*v3.z; acc3.w += w*v3.w;
        den += w;

        v0 = n0; v1 = n1; v2 = n2; v3 = n3;
    }

    // reduce accumulators across the 4 sub-groups (lane bits 4,5)
    #define XRED(x) x += __shfl_xor(x, 16, 64); x += __shfl_xor(x, 32, 64)
    XRED(acc0.x); XRED(acc0.y); XRED(acc0.z); XRED(acc0.w);
    XRED(acc1.x); XRED(acc1.y); XRED(acc1.z); XRED(acc1.w);
    XRED(acc2.x); XRED(acc2.y); XRED(acc2.z); XRED(acc2.w);
    XRED(acc3.x); XRED(acc3.y); XRED(acc3.z); XRED(acc3.w);
    XRED(den);
    #undef XRED

    // combine 4 waves via LDS, write per-block partials
    __shared__ float s_num[4][HID];
    __shared__ float s_den[4];
    if (sub == 0) {
        float4* dst = (float4*)s_num[wv];
        dst[pos]      = acc0;
        dst[pos + 16] = acc1;
        dst[pos + 32] = acc2;
        dst[pos + 48] = acc3;
    }
    if (lane == 0) s_den[wv] = den;
    __syncthreads();

    const int blk = b * SPLIT + split;
    float n = s_num[0][tid] + s_num[1][tid] + s_num[2][tid] + s_num[3][tid];
    numP[(size_t)blk * HID + tid] = n;
    if (tid == 0) denP[blk] = s_den[0] + s_den[1] + s_den[2] + s_den[3];
}

// ---------------- Kernel 3: reduce partials, normalize ----------------
__global__ __launch_bounds__(256) void reduce_kernel(const float* __restrict__ numP,
                                                     const float* __restrict__ denP,
                                                     float* __restrict__ out) {
    const int b = blockIdx.x;
    const int h = threadIdx.x;
    float num = 0.0f, den = 0.0f;
    #pragma unroll
    for (int s = 0; s < SPLIT; ++s) {
        num += numP[(size_t)(b * SPLIT + s) * HID + h];
        den += denP[b * SPLIT + s];
    }
    out[b * HID + h] = num / den;
}

extern "C" void kernel_launch(void* const* d_in, const int* in_sizes, int n_in,
                              void* d_out, int out_size, void* d_ws, size_t ws_size,
                              hipStream_t stream) {
    const float* A = (const float*)d_in[0];    // [64,512]
    const float* B = (const float*)d_in[1];    // [64,8192,256]
    const float* W = (const float*)d_in[2];    // [256,512]
    const float* bias = (const float*)d_in[3]; // [256]
    float* out = (float*)d_out;                // [64,1,256]

    float* AP = (float*)d_ws;
    float* numP = AP + BATCH * HID;
    float* denP = numP + BATCH * SPLIT * HID;

    ap_kernel<<<BATCH, 256, 0, stream>>>(A, W, bias, AP);
    pool_kernel<<<dim3(SPLIT, BATCH), 256, 0, stream>>>(B, AP, numP, denP);
    reduce_kernel<<<BATCH, 256, 0, stream>>>(numP, denP, out);
}

// Round 4
// 107.508 us; speedup vs baseline: 2.9918x; 1.1531x over previous
//
#include <hip/hip_runtime.h>

// AttentionalPoolingMechanism: fused single-pass attention pooling.
// A[64,512] f32, B[64,8192,256] f32, W[256,512] f32, b[256] f32 -> out[64,1,256] f32.
//
// AP = tanh(A@W^T + b); s_t = <AP_b, B[b,t,:]>; w_t = exp(-s_t)/sum; out = sum_t w_t B[b,t,:]
// No max-subtraction needed (reference does bare exp(-R); |s| <~ 40 fits f32).
//
// Pool pass (round 4): 16 lanes/row, 8 rows per wave-iteration as two
// independent 4-row groups -> two interleavable 4-step shfl chains, 8 KB/wave
// of loads in flight, nontemporal B loads (pure stream, no reuse).
// Round-2 lesson: no tight min-waves clamp ((256,4) capped VGPR=64 -> 484 MB spill).

#define BATCH 64
#define T_LEN 8192
#define FEAT 512
#define HID 256
#define SPLIT 32                       // blocks per batch in pool pass
#define ROWS_PER_BLOCK (T_LEN / SPLIT) // 256
#define ROWS_PER_WAVE 64
#define ITERS (ROWS_PER_WAVE / 8)      // 8

typedef float f4 __attribute__((ext_vector_type(4)));

__device__ __forceinline__ f4 ntl(const f4* p) { return __builtin_nontemporal_load(p); }
__device__ __forceinline__ float hsum(f4 v) { return (v.x + v.y) + (v.z + v.w); }

// ---------------- Kernel 1: AP = tanh(A @ W^T + bias) ----------------
__global__ __launch_bounds__(256) void ap_kernel(const float* __restrict__ A,
                                                 const float* __restrict__ W,
                                                 const float* __restrict__ bias,
                                                 float* __restrict__ AP) {
    const int b = blockIdx.x;
    const int tid = threadIdx.x;

    __shared__ float sA[FEAT];
    __shared__ float sW[HID * 33]; // 256 rows x 32 k, padded stride 33 -> 2-way max (free)

    sA[tid] = A[b * FEAT + tid];
    sA[tid + 256] = A[b * FEAT + tid + 256];

    float acc = 0.0f;
    for (int k0 = 0; k0 < FEAT; k0 += 32) {
        __syncthreads();
        #pragma unroll
        for (int t = 0; t < 8; ++t) {
            int f = t * 256 + tid;
            int h = f >> 3;
            int kq = f & 7;
            float4 v = *(const float4*)(W + (size_t)h * FEAT + k0 + kq * 4);
            float* dst = &sW[h * 33 + kq * 4];
            dst[0] = v.x; dst[1] = v.y; dst[2] = v.z; dst[3] = v.w;
        }
        __syncthreads();
        #pragma unroll
        for (int k = 0; k < 32; ++k)
            acc += sA[k0 + k] * sW[tid * 33 + k];
    }
    acc += bias[tid];
    AP[b * HID + tid] = tanhf(acc);
}

// ---------------- Kernel 2: fused score+exp+weighted-accumulate ----------------
// grid = (SPLIT, BATCH), 256 threads = 4 waves; wave owns 64 consecutive rows.
// Lane (sub = lane>>4, pos = lane&15): group-A row = base + sub, group-B row =
// base + 4 + sub. Each lane holds one row's 4 float4 slices (pos + 16j).
// Per-instruction footprint: 4 rows x 256B contiguous segments (coalesced).
__global__ __launch_bounds__(256) void pool_kernel(const float* __restrict__ B,
                                                   const float* __restrict__ AP,
                                                   float* __restrict__ numP,
                                                   float* __restrict__ denP) {
    const int split = blockIdx.x;
    const int b = blockIdx.y;
    const int tid = threadIdx.x;
    const int wv = tid >> 6;
    const int lane = tid & 63;
    const int sub = lane >> 4;
    const int pos = lane & 15;

    const f4* __restrict__ AP4 = (const f4*)(AP + b * HID);
    const f4 ap0 = AP4[pos];
    const f4 ap1 = AP4[pos + 16];
    const f4 ap2 = AP4[pos + 32];
    const f4 ap3 = AP4[pos + 48];

    const f4* __restrict__ B4 = (const f4*)(B) + (size_t)b * T_LEN * (HID / 4);
    const int row0 = split * ROWS_PER_BLOCK + wv * ROWS_PER_WAVE;

    f4 acc0 = {0.f,0.f,0.f,0.f}, acc1 = {0.f,0.f,0.f,0.f};
    f4 acc2 = {0.f,0.f,0.f,0.f}, acc3 = {0.f,0.f,0.f,0.f};
    float den = 0.0f;

    // prologue: load iteration 0 (rows base+sub and base+4+sub)
    const f4* pa = B4 + (size_t)(row0 + sub) * (HID / 4);
    const f4* pb = pa + 4 * (HID / 4);
    f4 vA0 = ntl(pa + pos), vA1 = ntl(pa + pos + 16), vA2 = ntl(pa + pos + 32), vA3 = ntl(pa + pos + 48);
    f4 vB0 = ntl(pb + pos), vB1 = ntl(pb + pos + 16), vB2 = ntl(pb + pos + 32), vB3 = ntl(pb + pos + 48);

    #pragma unroll
    for (int it = 0; it < ITERS; ++it) {
        // 1-iteration prefetch (8 rows ahead); clamp is compile-time (full unroll)
        const int nit = (it + 1 < ITERS) ? it + 1 : ITERS - 1;
        const f4* na = B4 + (size_t)(row0 + nit * 8 + sub) * (HID / 4);
        const f4* nb = na + 4 * (HID / 4);
        f4 nA0 = ntl(na + pos), nA1 = ntl(na + pos + 16), nA2 = ntl(na + pos + 32), nA3 = ntl(na + pos + 48);
        f4 nB0 = ntl(nb + pos), nB1 = ntl(nb + pos + 16), nB2 = ntl(nb + pos + 32), nB3 = ntl(nb + pos + 48);

        f4 mA = vA0 * ap0 + vA1 * ap1 + vA2 * ap2 + vA3 * ap3;
        f4 mB = vB0 * ap0 + vB1 * ap1 + vB2 * ap2 + vB3 * ap3;
        float pAs = hsum(mA);
        float pBs = hsum(mB);

        // two independent 4-step butterflies (16-lane groups) — interleave
        pAs += __shfl_xor(pAs, 8, 64);
        pBs += __shfl_xor(pBs, 8, 64);
        pAs += __shfl_xor(pAs, 4, 64);
        pBs += __shfl_xor(pBs, 4, 64);
        pAs += __shfl_xor(pAs, 2, 64);
        pBs += __shfl_xor(pBs, 2, 64);
        pAs += __shfl_xor(pAs, 1, 64);
        pBs += __shfl_xor(pBs, 1, 64);

        const float wA = __expf(-pAs);
        const float wB = __expf(-pBs);
        acc0 += wA * vA0 + wB * vB0;
        acc1 += wA * vA1 + wB * vB1;
        acc2 += wA * vA2 + wB * vB2;
        acc3 += wA * vA3 + wB * vB3;
        den += wA + wB;

        vA0 = nA0; vA1 = nA1; vA2 = nA2; vA3 = nA3;
        vB0 = nB0; vB1 = nB1; vB2 = nB2; vB3 = nB3;
    }

    // reduce accumulators across the 4 sub-groups (lane bits 4,5)
    #define XRED(x) x += __shfl_xor(x, 16, 64); x += __shfl_xor(x, 32, 64)
    XRED(acc0.x); XRED(acc0.y); XRED(acc0.z); XRED(acc0.w);
    XRED(acc1.x); XRED(acc1.y); XRED(acc1.z); XRED(acc1.w);
    XRED(acc2.x); XRED(acc2.y); XRED(acc2.z); XRED(acc2.w);
    XRED(acc3.x); XRED(acc3.y); XRED(acc3.z); XRED(acc3.w);
    XRED(den);
    #undef XRED

    // combine 4 waves via LDS, write per-block partials
    __shared__ float s_num[4][HID];
    __shared__ float s_den[4];
    if (sub == 0) {
        f4* dst = (f4*)s_num[wv];
        dst[pos]      = acc0;
        dst[pos + 16] = acc1;
        dst[pos + 32] = acc2;
        dst[pos + 48] = acc3;
    }
    if (lane == 0) s_den[wv] = den;
    __syncthreads();

    const int blk = b * SPLIT + split;
    float n = s_num[0][tid] + s_num[1][tid] + s_num[2][tid] + s_num[3][tid];
    numP[(size_t)blk * HID + tid] = n;
    if (tid == 0) denP[blk] = s_den[0] + s_den[1] + s_den[2] + s_den[3];
}

// ---------------- Kernel 3: reduce partials, normalize ----------------
__global__ __launch_bounds__(256) void reduce_kernel(const float* __restrict__ numP,
                                                     const float* __restrict__ denP,
                                                     float* __restrict__ out) {
    const int b = blockIdx.x;
    const int h = threadIdx.x;
    float num = 0.0f, den = 0.0f;
    #pragma unroll
    for (int s = 0; s < SPLIT; ++s) {
        num += numP[(size_t)(b * SPLIT + s) * HID + h];
        den += denP[b * SPLIT + s];
    }
    out[b * HID + h] = num / den;
}

extern "C" void kernel_launch(void* const* d_in, const int* in_sizes, int n_in,
                              void* d_out, int out_size, void* d_ws, size_t ws_size,
                              hipStream_t stream) {
    const float* A = (const float*)d_in[0];    // [64,512]
    const float* B = (const float*)d_in[1];    // [64,8192,256]
    const float* W = (const float*)d_in[2];    // [256,512]
    const float* bias = (const float*)d_in[3]; // [256]
    float* out = (float*)d_out;                // [64,1,256]

    float* AP = (float*)d_ws;
    float* numP = AP + BATCH * HID;
    float* denP = numP + BATCH * SPLIT * HID;

    ap_kernel<<<BATCH, 256, 0, stream>>>(A, W, bias, AP);
    pool_kernel<<<dim3(SPLIT, BATCH), 256, 0, stream>>>(B, AP, numP, denP);
    reduce_kernel<<<BATCH, 256, 0, stream>>>(numP, denP, out);
}

// Round 5
// 96.849 us; speedup vs baseline: 3.3211x; 1.1101x over previous
//
#include <hip/hip_runtime.h>

// AttentionalPoolingMechanism: fused single-pass attention pooling.
// A[64,512] f32, B[64,8192,256] f32, W[256,512] f32, b[256] f32 -> out[64,1,256] f32.
//
// AP = tanh(A@W^T + b); s_t = <AP_b, B[b,t,:]>; w_t = exp(-s_t)/sum; out = sum_t w_t B[b,t,:]
// No max-subtraction needed (reference does bare exp(-R); |s| <~ 40 fits f32).
//
// R5: (1) peel last pool iteration — the clamped redundant prefetch re-read
// 64 MB from HBM since nt loads bypass cache (R4 post-mortem); (2) 16-lane
// allreduce via DPP (quad_perm xor1/xor2, row_ror:8, row_ror:4 — VALU ~4cyc)
// instead of __shfl_xor (DS ~30cyc); (3) ap_kernel parallelized to 256 blocks,
// W read straight from L2 (no LDS staging).
// R2 lesson: no tight min-waves clamp ((256,4) capped VGPR=64 -> 484 MB spill).

#define BATCH 64
#define T_LEN 8192
#define FEAT 512
#define HID 256
#define SPLIT 32                       // blocks per batch in pool pass
#define ROWS_PER_BLOCK (T_LEN / SPLIT) // 256
#define ROWS_PER_WAVE 64
#define ITERS (ROWS_PER_WAVE / 8)      // 8

typedef float f4 __attribute__((ext_vector_type(4)));

__device__ __forceinline__ f4 ntl(const f4* p) { return __builtin_nontemporal_load(p); }
__device__ __forceinline__ float hsum(f4 v) { return (v.x + v.y) + (v.z + v.w); }

// DPP add: x + permuted(x). CTRL: 0xB1 quad_perm xor1, 0x4E quad_perm xor2,
// 0x128 row_ror:8, 0x124 row_ror:4 (row = 16 lanes).
template <int CTRL>
__device__ __forceinline__ float dpp_add(float x) {
    int y = __builtin_amdgcn_update_dpp(0, __float_as_int(x), CTRL, 0xF, 0xF, true);
    return x + __int_as_float(y);
}
// 16-lane allreduce: quads sum via xor1/xor2, then ror8 pairs q0+q2|q1+q3,
// ror4 combines the two pair-sums -> every lane holds the row total.
__device__ __forceinline__ float row16_allreduce(float x) {
    x = dpp_add<0xB1>(x);
    x = dpp_add<0x4E>(x);
    x = dpp_add<0x128>(x);
    x = dpp_add<0x124>(x);
    return x;
}

// ---------------- Kernel 1: AP = tanh(A @ W^T + bias) ----------------
// grid (4, BATCH), 256 thr. Block (p,b) computes AP[b][p*64 .. p*64+63].
// 16 lanes per output row; W rows read directly (L2-hot), no LDS staging.
__global__ __launch_bounds__(256) void ap_kernel(const float* __restrict__ A,
                                                 const float* __restrict__ W,
                                                 const float* __restrict__ bias,
                                                 float* __restrict__ AP) {
    const int p = blockIdx.x;
    const int b = blockIdx.y;
    const int tid = threadIdx.x;
    const int pos = tid & 15;

    __shared__ float sA[FEAT];
    sA[tid] = A[b * FEAT + tid];
    sA[tid + 256] = A[b * FEAT + tid + 256];
    __syncthreads();

    // A fragment in regs: a[j] covers k = 4*pos + 64*j .. +3
    const f4* sA4 = (const f4*)sA;
    f4 a0 = sA4[pos],      a1 = sA4[pos + 16], a2 = sA4[pos + 32], a3 = sA4[pos + 48];
    f4 a4 = sA4[pos + 64], a5 = sA4[pos + 80], a6 = sA4[pos + 96], a7 = sA4[pos + 112];

    #pragma unroll
    for (int pass = 0; pass < 4; ++pass) {
        const int h = p * 64 + pass * 16 + (tid >> 4);
        const f4* Wr = (const f4*)(W + (size_t)h * FEAT);
        f4 m = Wr[pos] * a0 + Wr[pos + 16] * a1 + Wr[pos + 32] * a2 + Wr[pos + 48] * a3
             + Wr[pos + 64] * a4 + Wr[pos + 80] * a5 + Wr[pos + 96] * a6 + Wr[pos + 112] * a7;
        float s = row16_allreduce(hsum(m));
        if (pos == 0) AP[b * HID + h] = tanhf(s + bias[h]);
    }
}

// ---------------- Kernel 2: fused score+exp+weighted-accumulate ----------------
// grid = (SPLIT, BATCH), 256 threads = 4 waves; wave owns 64 consecutive rows.
// Lane (sub = lane>>4, pos = lane&15): group-A row = base + sub, group-B row =
// base + 4 + sub. Per-instruction footprint: 4 rows x 256B contiguous segments.
__global__ __launch_bounds__(256) void pool_kernel(const float* __restrict__ B,
                                                   const float* __restrict__ AP,
                                                   float* __restrict__ numP,
                                                   float* __restrict__ denP) {
    const int split = blockIdx.x;
    const int b = blockIdx.y;
    const int tid = threadIdx.x;
    const int wv = tid >> 6;
    const int lane = tid & 63;
    const int sub = lane >> 4;
    const int pos = lane & 15;

    const f4* __restrict__ AP4 = (const f4*)(AP + b * HID);
    const f4 ap0 = AP4[pos];
    const f4 ap1 = AP4[pos + 16];
    const f4 ap2 = AP4[pos + 32];
    const f4 ap3 = AP4[pos + 48];

    const f4* __restrict__ B4 = (const f4*)(B) + (size_t)b * T_LEN * (HID / 4);
    const int row0 = split * ROWS_PER_BLOCK + wv * ROWS_PER_WAVE;

    f4 acc0 = {0.f,0.f,0.f,0.f}, acc1 = {0.f,0.f,0.f,0.f};
    f4 acc2 = {0.f,0.f,0.f,0.f}, acc3 = {0.f,0.f,0.f,0.f};
    float den = 0.0f;

    // prologue: load iteration 0 (rows base+sub and base+4+sub)
    const f4* pa = B4 + (size_t)(row0 + sub) * (HID / 4);
    const f4* pb = pa + 4 * (HID / 4);
    f4 vA0 = ntl(pa + pos), vA1 = ntl(pa + pos + 16), vA2 = ntl(pa + pos + 32), vA3 = ntl(pa + pos + 48);
    f4 vB0 = ntl(pb + pos), vB1 = ntl(pb + pos + 16), vB2 = ntl(pb + pos + 32), vB3 = ntl(pb + pos + 48);

    #pragma unroll
    for (int it = 0; it < ITERS; ++it) {
        // 1-iteration prefetch; PEELED on the last iteration (it+1 test is
        // compile-time under full unroll) — no redundant nt re-reads from HBM.
        f4 nA0, nA1, nA2, nA3, nB0, nB1, nB2, nB3;
        if (it + 1 < ITERS) {
            const f4* na = B4 + (size_t)(row0 + (it + 1) * 8 + sub) * (HID / 4);
            const f4* nb = na + 4 * (HID / 4);
            nA0 = ntl(na + pos); nA1 = ntl(na + pos + 16); nA2 = ntl(na + pos + 32); nA3 = ntl(na + pos + 48);
            nB0 = ntl(nb + pos); nB1 = ntl(nb + pos + 16); nB2 = ntl(nb + pos + 32); nB3 = ntl(nb + pos + 48);
        }

        f4 mA = vA0 * ap0 + vA1 * ap1 + vA2 * ap2 + vA3 * ap3;
        f4 mB = vB0 * ap0 + vB1 * ap1 + vB2 * ap2 + vB3 * ap3;
        float pAs = hsum(mA);
        float pBs = hsum(mB);

        // two independent 16-lane DPP allreduces — VALU-latency, interleaved
        pAs = dpp_add<0xB1>(pAs);  pBs = dpp_add<0xB1>(pBs);
        pAs = dpp_add<0x4E>(pAs);  pBs = dpp_add<0x4E>(pBs);
        pAs = dpp_add<0x128>(pAs); pBs = dpp_add<0x128>(pBs);
        pAs = dpp_add<0x124>(pAs); pBs = dpp_add<0x124>(pBs);

        const float wA = __expf(-pAs);
        const float wB = __expf(-pBs);
        acc0 += wA * vA0 + wB * vB0;
        acc1 += wA * vA1 + wB * vB1;
        acc2 += wA * vA2 + wB * vB2;
        acc3 += wA * vA3 + wB * vB3;
        den += wA + wB;

        if (it + 1 < ITERS) {
            vA0 = nA0; vA1 = nA1; vA2 = nA2; vA3 = nA3;
            vB0 = nB0; vB1 = nB1; vB2 = nB2; vB3 = nB3;
        }
    }

    // reduce accumulators across the 4 sub-groups (lane bits 4,5)
    #define XRED(x) x += __shfl_xor(x, 16, 64); x += __shfl_xor(x, 32, 64)
    XRED(acc0.x); XRED(acc0.y); XRED(acc0.z); XRED(acc0.w);
    XRED(acc1.x); XRED(acc1.y); XRED(acc1.z); XRED(acc1.w);
    XRED(acc2.x); XRED(acc2.y); XRED(acc2.z); XRED(acc2.w);
    XRED(acc3.x); XRED(acc3.y); XRED(acc3.z); XRED(acc3.w);
    XRED(den);
    #undef XRED

    // combine 4 waves via LDS, write per-block partials
    __shared__ float s_num[4][HID];
    __shared__ float s_den[4];
    if (sub == 0) {
        f4* dst = (f4*)s_num[wv];
        dst[pos]      = acc0;
        dst[pos + 16] = acc1;
        dst[pos + 32] = acc2;
        dst[pos + 48] = acc3;
    }
    if (lane == 0) s_den[wv] = den;
    __syncthreads();

    const int blk = b * SPLIT + split;
    float n = s_num[0][tid] + s_num[1][tid] + s_num[2][tid] + s_num[3][tid];
    numP[(size_t)blk * HID + tid] = n;
    if (tid == 0) denP[blk] = s_den[0] + s_den[1] + s_den[2] + s_den[3];
}

// ---------------- Kernel 3: reduce partials, normalize ----------------
__global__ __launch_bounds__(256) void reduce_kernel(const float* __restrict__ numP,
                                                     const float* __restrict__ denP,
                                                     float* __restrict__ out) {
    const int b = blockIdx.x;
    const int h = threadIdx.x;
    float num = 0.0f, den = 0.0f;
    #pragma unroll
    for (int s = 0; s < SPLIT; ++s) {
        num += numP[(size_t)(b * SPLIT + s) * HID + h];
        den += denP[b * SPLIT + s];
    }
    out[b * HID + h] = num / den;
}

extern "C" void kernel_launch(void* const* d_in, const int* in_sizes, int n_in,
                              void* d_out, int out_size, void* d_ws, size_t ws_size,
                              hipStream_t stream) {
    const float* A = (const float*)d_in[0];    // [64,512]
    const float* B = (const float*)d_in[1];    // [64,8192,256]
    const float* W = (const float*)d_in[2];    // [256,512]
    const float* bias = (const float*)d_in[3]; // [256]
    float* out = (float*)d_out;                // [64,1,256]

    float* AP = (float*)d_ws;
    float* numP = AP + BATCH * HID;
    float* denP = numP + BATCH * SPLIT * HID;

    ap_kernel<<<dim3(4, BATCH), 256, 0, stream>>>(A, W, bias, AP);
    pool_kernel<<<dim3(SPLIT, BATCH), 256, 0, stream>>>(B, AP, numP, denP);
    reduce_kernel<<<BATCH, 256, 0, stream>>>(numP, denP, out);
}